// Round 1
// baseline (536.776 us; speedup 1.0000x reference)
//
#include <hip/hip_runtime.h>

#define TT 25000
#define BB 2
#define CC 128
#define NN (BB*TT)   // 50000 nodes

// ---------------- degree count ----------------
__global__ void k_deg(const int* __restrict__ dst, int E, int* __restrict__ deg) {
    int i = blockIdx.x * blockDim.x + threadIdx.x;
    if (i < E) atomicAdd(&deg[dst[i]], 1);
}

// ---------------- dinv_sqrt = rsqrt(deg+1) ----------------
__global__ void k_dinv(const int* __restrict__ deg, float* __restrict__ dinv) {
    int i = blockIdx.x * blockDim.x + threadIdx.x;
    if (i < NN) {
        float d = (float)(deg[i] + 1);
        dinv[i] = rsqrtf(d);
    }
}

// ---------------- exclusive scan (single block, 1024 threads) ----------------
__global__ void k_scan(const int* __restrict__ deg, int* __restrict__ off) {
    __shared__ int part[1024];
    int tid = threadIdx.x;
    const int chunk = (NN + 1023) / 1024;           // 49
    int b0 = tid * chunk;
    int b1 = b0 + chunk; if (b1 > NN) b1 = NN;
    if (b0 > NN) b0 = NN;
    int s = 0;
    for (int i = b0; i < b1; ++i) s += deg[i];
    part[tid] = s;
    __syncthreads();
    for (int o = 1; o < 1024; o <<= 1) {
        int v = (tid >= o) ? part[tid - o] : 0;
        __syncthreads();
        part[tid] += v;
        __syncthreads();
    }
    int run = (tid == 0) ? 0 : part[tid - 1];
    for (int i = b0; i < b1; ++i) { off[i] = run; run += deg[i]; }
    if (tid == 1023) off[NN] = run;                 // == E
}

// ---------------- CSR fill ----------------
__global__ void k_fill(const int* __restrict__ src, const int* __restrict__ dst, int E,
                       const int* __restrict__ off, int* __restrict__ cur,
                       int* __restrict__ csr_src) {
    int i = blockIdx.x * blockDim.x + threadIdx.x;
    if (i < E) {
        int d = dst[i];
        int p = off[d] + atomicAdd(&cur[d], 1);
        csr_src[p] = src[i];
    }
}

// ---------------- GEMM: h[n][oc] = sum_c x[b][c][t] * W[c][oc] ----------------
__global__ __launch_bounds__(256) void k_gemm(const float* __restrict__ x,
                                              const float* __restrict__ W,
                                              float* __restrict__ h) {
    __shared__ float xs[32][129];                   // +1 pad: conflict-free
    int n0 = blockIdx.x * 32;
    int tid = threadIdx.x;

    // load phase: 32 consecutive nodes (t-consecutive) per row of c
    int nl = tid & 31;
    int cc = tid >> 5;                              // 0..7
    int n = n0 + nl;
    int bidx = 0, t = 0;
    bool ok = (n < NN);
    if (ok) { bidx = n / TT; t = n - bidx * TT; }
    for (int c = cc; c < CC; c += 8) {
        float v = 0.f;
        if (ok) v = x[(bidx * CC + c) * TT + t];
        xs[nl][c] = v;
    }
    __syncthreads();

    // compute phase: thread -> (node nr, 16 oc starting at og*16)
    int og = tid & 7;
    int nr = tid >> 3;                              // 0..31
    float acc[16];
#pragma unroll
    for (int j = 0; j < 16; ++j) acc[j] = 0.f;
    const float4* W4 = (const float4*)W;
    for (int c = 0; c < CC; ++c) {
        float a = xs[nr][c];
        float4 w0 = W4[c * 32 + og * 4 + 0];
        float4 w1 = W4[c * 32 + og * 4 + 1];
        float4 w2 = W4[c * 32 + og * 4 + 2];
        float4 w3 = W4[c * 32 + og * 4 + 3];
        acc[0]  = fmaf(a, w0.x, acc[0]);  acc[1]  = fmaf(a, w0.y, acc[1]);
        acc[2]  = fmaf(a, w0.z, acc[2]);  acc[3]  = fmaf(a, w0.w, acc[3]);
        acc[4]  = fmaf(a, w1.x, acc[4]);  acc[5]  = fmaf(a, w1.y, acc[5]);
        acc[6]  = fmaf(a, w1.z, acc[6]);  acc[7]  = fmaf(a, w1.w, acc[7]);
        acc[8]  = fmaf(a, w2.x, acc[8]);  acc[9]  = fmaf(a, w2.y, acc[9]);
        acc[10] = fmaf(a, w2.z, acc[10]); acc[11] = fmaf(a, w2.w, acc[11]);
        acc[12] = fmaf(a, w3.x, acc[12]); acc[13] = fmaf(a, w3.y, acc[13]);
        acc[14] = fmaf(a, w3.z, acc[14]); acc[15] = fmaf(a, w3.w, acc[15]);
    }
    int no = n0 + nr;
    if (no < NN) {
        float4* h4 = (float4*)(h + (size_t)no * CC + og * 16);
        h4[0] = make_float4(acc[0],  acc[1],  acc[2],  acc[3]);
        h4[1] = make_float4(acc[4],  acc[5],  acc[6],  acc[7]);
        h4[2] = make_float4(acc[8],  acc[9],  acc[10], acc[11]);
        h4[3] = make_float4(acc[12], acc[13], acc[14], acc[15]);
    }
}

// ---------------- aggregation: one wave per node, CSR gather ----------------
__global__ __launch_bounds__(256) void k_agg(const float* __restrict__ h,
                                             const int* __restrict__ off,
                                             const int* __restrict__ csr_src,
                                             const float* __restrict__ dinv,
                                             const float* __restrict__ bias,
                                             float* __restrict__ agg) {
    int lane = threadIdx.x & 63;
    int w    = threadIdx.x >> 6;
    int n    = blockIdx.x * 4 + w;
    if (n >= NN) return;
    const float2* h2 = (const float2*)h;
    float2 acc = make_float2(0.f, 0.f);
    int e0 = off[n], e1 = off[n + 1];
    for (int e = e0; e < e1; ++e) {
        int s   = csr_src[e];
        float f = dinv[s];
        float2 v = h2[(size_t)s * 64 + lane];
        acc.x = fmaf(f, v.x, acc.x);
        acc.y = fmaf(f, v.y, acc.y);
    }
    float di = dinv[n];
    float2 hv = h2[(size_t)n * 64 + lane];
    const float2* b2 = (const float2*)bias;
    float2 bb = b2[lane];
    float rx = fmaf(di, acc.x, di * di * hv.x) + bb.x;
    float ry = fmaf(di, acc.y, di * di * hv.y) + bb.y;
    rx = fmaxf(rx, 0.f);
    ry = fmaxf(ry, 0.f);
    ((float2*)agg)[(size_t)n * 64 + lane] = make_float2(rx, ry);
}

// ---------------- transpose [n][oc] -> [b][oc][t] ----------------
__global__ void k_trans(const float* __restrict__ agg, float* __restrict__ out) {
    __shared__ float tile[32][33];
    int t0 = blockIdx.x * 32;
    int o0 = blockIdx.y * 32;
    int b  = blockIdx.z;
    int tx = threadIdx.x, ty = threadIdx.y;         // 32 x 8
#pragma unroll
    for (int i = 0; i < 4; ++i) {
        int t = t0 + ty + i * 8;
        if (t < TT) tile[ty + i * 8][tx] = agg[(size_t)(b * TT + t) * CC + o0 + tx];
    }
    __syncthreads();
#pragma unroll
    for (int i = 0; i < 4; ++i) {
        int t  = t0 + tx;
        int oc = o0 + ty + i * 8;
        if (t < TT) out[((size_t)b * CC + oc) * TT + t] = tile[tx][ty + i * 8];
    }
}

extern "C" void kernel_launch(void* const* d_in, const int* in_sizes, int n_in,
                              void* d_out, int out_size, void* d_ws, size_t ws_size,
                              hipStream_t stream) {
    const float* x    = (const float*)d_in[0];
    const float* W    = (const float*)d_in[1];
    const float* bias = (const float*)d_in[2];
    const int*   ei   = (const int*)d_in[3];
    int E = in_sizes[3] / 2;
    const int* src = ei;
    const int* dst = ei + E;
    float* out = (float*)d_out;

    char* ws = (char*)d_ws;
    size_t o = 0;
    float* h    = (float*)(ws + o); o += (size_t)NN * CC * 4;       // 25.6 MB
    float* agg  = (float*)(ws + o); o += (size_t)NN * CC * 4;       // 25.6 MB
    int*   deg  = (int*)  (ws + o); o += (size_t)NN * 4;
    float* dinv = (float*)(ws + o); o += (size_t)NN * 4;
    int*   off  = (int*)  (ws + o); o += (size_t)(NN + 1) * 4 + 12; // keep 16B align
    int*   cur  = (int*)  (ws + o); o += (size_t)NN * 4;
    int*   csrs = (int*)  (ws + o); o += (size_t)E * 4;

    hipMemsetAsync(deg, 0, (size_t)NN * 4, stream);
    hipMemsetAsync(cur, 0, (size_t)NN * 4, stream);

    k_deg <<<(E + 255) / 256, 256, 0, stream>>>(dst, E, deg);
    k_dinv<<<(NN + 255) / 256, 256, 0, stream>>>(deg, dinv);
    k_scan<<<1, 1024, 0, stream>>>(deg, off);
    k_fill<<<(E + 255) / 256, 256, 0, stream>>>(src, dst, E, off, cur, csrs);
    k_gemm<<<(NN + 31) / 32, 256, 0, stream>>>(x, W, h);
    k_agg <<<(NN + 3) / 4, 256, 0, stream>>>(h, off, csrs, dinv, bias, agg);
    dim3 tg((TT + 31) / 32, CC / 32, BB);
    k_trans<<<tg, dim3(32, 8), 0, stream>>>(agg, out);
}

// Round 2
// 389.576 us; speedup vs baseline: 1.3778x; 1.3778x over previous
//
#include <hip/hip_runtime.h>

#define TT 25000
#define BB 2
#define CC 128
#define NN (BB*TT)   // 50000 nodes

// ---------------- degree count ----------------
__global__ void k_deg(const int* __restrict__ dst, int E, int* __restrict__ deg) {
    int i = blockIdx.x * blockDim.x + threadIdx.x;
    if (i < E) atomicAdd(&deg[dst[i]], 1);
}

// ---------------- exclusive scan (single block, 1024 threads) + dinv ----------------
__global__ void k_scan(const int* __restrict__ deg, int* __restrict__ off,
                       float* __restrict__ dinv) {
    __shared__ int part[1024];
    int tid = threadIdx.x;
    const int chunk = (NN + 1023) / 1024;           // 49
    int b0 = tid * chunk;
    int b1 = b0 + chunk; if (b1 > NN) b1 = NN;
    if (b0 > NN) b0 = NN;
    int s = 0;
    for (int i = b0; i < b1; ++i) s += deg[i];
    part[tid] = s;
    __syncthreads();
    for (int o = 1; o < 1024; o <<= 1) {
        int v = (tid >= o) ? part[tid - o] : 0;
        __syncthreads();
        part[tid] += v;
        __syncthreads();
    }
    int run = (tid == 0) ? 0 : part[tid - 1];
    for (int i = b0; i < b1; ++i) {
        off[i] = run;
        run += deg[i];
        dinv[i] = rsqrtf((float)(deg[i] + 1));
    }
    if (tid == 1023) off[NN] = run;                 // == E
}

// ---------------- CSR fill ----------------
__global__ void k_fill(const int* __restrict__ src, const int* __restrict__ dst, int E,
                       const int* __restrict__ off, int* __restrict__ cur,
                       int* __restrict__ csr_src) {
    int i = blockIdx.x * blockDim.x + threadIdx.x;
    if (i < E) {
        int d = dst[i];
        int p = off[d] + atomicAdd(&cur[d], 1);
        csr_src[p] = src[i];
    }
}

// ---------------- GEMM: h[n][oc] = sum_c x[b][c][t] * W[c][oc] ----------------
// Register-tiled: block = 64 nodes x 128 oc, BK=32 k-slab in LDS.
// Thread tile: 4 nodes x 8 oc (two float4 halves at tx*4 and 64+tx*4).
#define BN 64
#define BK 32
__global__ __launch_bounds__(256) void k_gemm(const float* __restrict__ x,
                                              const float* __restrict__ W,
                                              float* __restrict__ h) {
    __shared__ float xs[BK][BN + 4];                // 8.7 KB
    __shared__ float ws[BK][CC + 4];                // 16.9 KB
    int tid = threadIdx.x;
    int n0 = blockIdx.x * BN;

    // x loader mapping: 64 nodes x 4 c-rows per pass
    int nl = tid & 63;
    int cl = tid >> 6;                              // 0..3
    int n = n0 + nl;
    bool ok = (n < NN);
    int b = 0, t = 0;
    if (ok) { b = n / TT; t = n - b * TT; }
    const float* xp = x + ((size_t)b * CC) * TT + t;

    // W loader mapping: 128 oc x 2 c-rows per pass
    int wl = tid & 127;
    int wc = tid >> 7;                              // 0..1

    // compute mapping
    int tx = tid & 15;                              // oc group
    int ty = tid >> 4;                              // node group (0..15)

    float acc[4][8];
#pragma unroll
    for (int i = 0; i < 4; ++i)
#pragma unroll
        for (int j = 0; j < 8; ++j) acc[i][j] = 0.f;

    for (int k0 = 0; k0 < CC; k0 += BK) {
#pragma unroll
        for (int i = 0; i < BK / 4; ++i) {
            int c = cl + i * 4;
            xs[c][nl] = ok ? xp[(size_t)(k0 + c) * TT] : 0.f;
        }
#pragma unroll
        for (int i = 0; i < BK / 2; ++i) {
            int c = wc + i * 2;
            ws[c][wl] = W[(k0 + c) * CC + wl];
        }
        __syncthreads();
#pragma unroll 8
        for (int k = 0; k < BK; ++k) {
            float4 a0 = *(const float4*)&xs[k][ty * 4];
            float4 b0 = *(const float4*)&ws[k][tx * 4];
            float4 b1 = *(const float4*)&ws[k][64 + tx * 4];
            acc[0][0] = fmaf(a0.x, b0.x, acc[0][0]); acc[0][1] = fmaf(a0.x, b0.y, acc[0][1]);
            acc[0][2] = fmaf(a0.x, b0.z, acc[0][2]); acc[0][3] = fmaf(a0.x, b0.w, acc[0][3]);
            acc[0][4] = fmaf(a0.x, b1.x, acc[0][4]); acc[0][5] = fmaf(a0.x, b1.y, acc[0][5]);
            acc[0][6] = fmaf(a0.x, b1.z, acc[0][6]); acc[0][7] = fmaf(a0.x, b1.w, acc[0][7]);
            acc[1][0] = fmaf(a0.y, b0.x, acc[1][0]); acc[1][1] = fmaf(a0.y, b0.y, acc[1][1]);
            acc[1][2] = fmaf(a0.y, b0.z, acc[1][2]); acc[1][3] = fmaf(a0.y, b0.w, acc[1][3]);
            acc[1][4] = fmaf(a0.y, b1.x, acc[1][4]); acc[1][5] = fmaf(a0.y, b1.y, acc[1][5]);
            acc[1][6] = fmaf(a0.y, b1.z, acc[1][6]); acc[1][7] = fmaf(a0.y, b1.w, acc[1][7]);
            acc[2][0] = fmaf(a0.z, b0.x, acc[2][0]); acc[2][1] = fmaf(a0.z, b0.y, acc[2][1]);
            acc[2][2] = fmaf(a0.z, b0.z, acc[2][2]); acc[2][3] = fmaf(a0.z, b0.w, acc[2][3]);
            acc[2][4] = fmaf(a0.z, b1.x, acc[2][4]); acc[2][5] = fmaf(a0.z, b1.y, acc[2][5]);
            acc[2][6] = fmaf(a0.z, b1.z, acc[2][6]); acc[2][7] = fmaf(a0.z, b1.w, acc[2][7]);
            acc[3][0] = fmaf(a0.w, b0.x, acc[3][0]); acc[3][1] = fmaf(a0.w, b0.y, acc[3][1]);
            acc[3][2] = fmaf(a0.w, b0.z, acc[3][2]); acc[3][3] = fmaf(a0.w, b0.w, acc[3][3]);
            acc[3][4] = fmaf(a0.w, b1.x, acc[3][4]); acc[3][5] = fmaf(a0.w, b1.y, acc[3][5]);
            acc[3][6] = fmaf(a0.w, b1.z, acc[3][6]); acc[3][7] = fmaf(a0.w, b1.w, acc[3][7]);
        }
        __syncthreads();
    }

#pragma unroll
    for (int i = 0; i < 4; ++i) {
        int no = n0 + ty * 4 + i;
        if (no < NN) {
            *(float4*)&h[(size_t)no * CC + tx * 4] =
                make_float4(acc[i][0], acc[i][1], acc[i][2], acc[i][3]);
            *(float4*)&h[(size_t)no * CC + 64 + tx * 4] =
                make_float4(acc[i][4], acc[i][5], acc[i][6], acc[i][7]);
        }
    }
}

// ---------------- aggregation: one wave per node, CSR gather ----------------
__global__ __launch_bounds__(256) void k_agg(const float* __restrict__ h,
                                             const int* __restrict__ off,
                                             const int* __restrict__ csr_src,
                                             const float* __restrict__ dinv,
                                             const float* __restrict__ bias,
                                             float* __restrict__ agg) {
    int lane = threadIdx.x & 63;
    int w    = threadIdx.x >> 6;
    int n    = blockIdx.x * 4 + w;
    if (n >= NN) return;
    const float2* h2 = (const float2*)h;
    float2 acc = make_float2(0.f, 0.f);
    int e0 = off[n], e1 = off[n + 1];
    for (int e = e0; e < e1; ++e) {
        int s   = csr_src[e];
        float f = dinv[s];
        float2 v = h2[(size_t)s * 64 + lane];
        acc.x = fmaf(f, v.x, acc.x);
        acc.y = fmaf(f, v.y, acc.y);
    }
    float di = dinv[n];
    float2 hv = h2[(size_t)n * 64 + lane];
    const float2* b2 = (const float2*)bias;
    float2 bb = b2[lane];
    float rx = fmaf(di, acc.x, di * di * hv.x) + bb.x;
    float ry = fmaf(di, acc.y, di * di * hv.y) + bb.y;
    rx = fmaxf(rx, 0.f);
    ry = fmaxf(ry, 0.f);
    ((float2*)agg)[(size_t)n * 64 + lane] = make_float2(rx, ry);
}

// ---------------- transpose [n][oc] -> [b][oc][t] ----------------
__global__ void k_trans(const float* __restrict__ agg, float* __restrict__ out) {
    __shared__ float tile[32][33];
    int t0 = blockIdx.x * 32;
    int o0 = blockIdx.y * 32;
    int b  = blockIdx.z;
    int tx = threadIdx.x, ty = threadIdx.y;         // 32 x 8
#pragma unroll
    for (int i = 0; i < 4; ++i) {
        int t = t0 + ty + i * 8;
        if (t < TT) tile[ty + i * 8][tx] = agg[(size_t)(b * TT + t) * CC + o0 + tx];
    }
    __syncthreads();
#pragma unroll
    for (int i = 0; i < 4; ++i) {
        int t  = t0 + tx;
        int oc = o0 + ty + i * 8;
        if (t < TT) out[((size_t)b * CC + oc) * TT + t] = tile[tx][ty + i * 8];
    }
}

extern "C" void kernel_launch(void* const* d_in, const int* in_sizes, int n_in,
                              void* d_out, int out_size, void* d_ws, size_t ws_size,
                              hipStream_t stream) {
    const float* x    = (const float*)d_in[0];
    const float* W    = (const float*)d_in[1];
    const float* bias = (const float*)d_in[2];
    const int*   ei   = (const int*)d_in[3];
    int E = in_sizes[3] / 2;
    const int* src = ei;
    const int* dst = ei + E;
    float* out = (float*)d_out;

    char* ws = (char*)d_ws;
    size_t o = 0;
    float* h    = (float*)(ws + o); o += (size_t)NN * CC * 4;       // 25.6 MB
    float* agg  = (float*)(ws + o); o += (size_t)NN * CC * 4;       // 25.6 MB
    int*   deg  = (int*)  (ws + o); o += (size_t)NN * 4;
    float* dinv = (float*)(ws + o); o += (size_t)NN * 4;
    int*   off  = (int*)  (ws + o); o += (size_t)(NN + 1) * 4 + 12; // keep 16B align
    int*   cur  = (int*)  (ws + o); o += (size_t)NN * 4;
    int*   csrs = (int*)  (ws + o); o += (size_t)E * 4;

    hipMemsetAsync(deg, 0, (size_t)NN * 4, stream);
    hipMemsetAsync(cur, 0, (size_t)NN * 4, stream);

    k_deg <<<(E + 255) / 256, 256, 0, stream>>>(dst, E, deg);
    k_scan<<<1, 1024, 0, stream>>>(deg, off, dinv);
    k_fill<<<(E + 255) / 256, 256, 0, stream>>>(src, dst, E, off, cur, csrs);
    k_gemm<<<(NN + BN - 1) / BN, 256, 0, stream>>>(x, W, h);
    k_agg <<<(NN + 3) / 4, 256, 0, stream>>>(h, off, csrs, dinv, bias, agg);
    dim3 tg((TT + 31) / 32, CC / 32, BB);
    k_trans<<<tg, dim3(32, 8), 0, stream>>>(agg, out);
}

// Round 3
// 291.655 us; speedup vs baseline: 1.8404x; 1.3357x over previous
//
#include <hip/hip_runtime.h>

#define TT 25000
#define BB 2
#define CC 128
#define NN (BB*TT)   // 50000 nodes
#define NB ((NN + 255) / 256)  // 196 scan blocks

// ---------------- degree count ----------------
__global__ void k_deg(const int* __restrict__ dst, int E, int* __restrict__ deg) {
    int i = blockIdx.x * blockDim.x + threadIdx.x;
    if (i < E) atomicAdd(&deg[dst[i]], 1);
}

// ---------------- scan pass 1: per-block sums ----------------
__global__ __launch_bounds__(256) void k_bsum(const int* __restrict__ deg,
                                              int* __restrict__ bsum) {
    __shared__ int red[256];
    int tid = threadIdx.x;
    int i = blockIdx.x * 256 + tid;
    red[tid] = (i < NN) ? deg[i] : 0;
    __syncthreads();
#pragma unroll
    for (int o = 128; o > 0; o >>= 1) {
        if (tid < o) red[tid] += red[tid + o];
        __syncthreads();
    }
    if (tid == 0) bsum[blockIdx.x] = red[0];
}

// ---------------- scan pass 2: block prefix + local scan + dinv ----------------
__global__ __launch_bounds__(256) void k_scan2(const int* __restrict__ deg,
                                               const int* __restrict__ bsum,
                                               int* __restrict__ off,
                                               float* __restrict__ dinv) {
    __shared__ int part[256];
    __shared__ int bpref;
    int tid = threadIdx.x;
    int i = blockIdx.x * 256 + tid;

    // prefix of block sums for blocks < blockIdx.x (NB=196 <= 256)
    part[tid] = (tid < NB && tid < blockIdx.x) ? bsum[tid] : 0;
    __syncthreads();
#pragma unroll
    for (int o = 128; o > 0; o >>= 1) {
        if (tid < o) part[tid] += part[tid + o];
        __syncthreads();
    }
    if (tid == 0) bpref = part[0];
    __syncthreads();
    int base = bpref;
    __syncthreads();

    // local inclusive scan (Hillis-Steele) of this block's 256 deg values
    int v = (i < NN) ? deg[i] : 0;
    part[tid] = v;
    __syncthreads();
#pragma unroll
    for (int o = 1; o < 256; o <<= 1) {
        int u = (tid >= o) ? part[tid - o] : 0;
        __syncthreads();
        part[tid] += u;
        __syncthreads();
    }
    int incl = part[tid];
    if (i < NN) {
        off[i]  = base + incl - v;                  // exclusive
        dinv[i] = rsqrtf((float)(v + 1));
    }
    if (i == NN - 1) off[NN] = base + incl;         // == E
}

// ---------------- CSR fill ----------------
__global__ void k_fill(const int* __restrict__ src, const int* __restrict__ dst, int E,
                       const int* __restrict__ off, int* __restrict__ cur,
                       int* __restrict__ csr_src) {
    int i = blockIdx.x * blockDim.x + threadIdx.x;
    if (i < E) {
        int d = dst[i];
        int p = off[d] + atomicAdd(&cur[d], 1);
        csr_src[p] = src[i];
    }
}

// ---------------- GEMM: h[n][oc] = sum_c x[b][c][t] * W[c][oc] ----------------
// Register-tiled: block = 64 nodes x 128 oc, BK=32 k-slab in LDS.
#define BN 64
#define BK 32
__global__ __launch_bounds__(256) void k_gemm(const float* __restrict__ x,
                                              const float* __restrict__ W,
                                              float* __restrict__ h) {
    __shared__ float xs[BK][BN + 4];
    __shared__ float ws[BK][CC + 4];
    int tid = threadIdx.x;
    int n0 = blockIdx.x * BN;

    int nl = tid & 63;
    int cl = tid >> 6;
    int n = n0 + nl;
    bool ok = (n < NN);
    int b = 0, t = 0;
    if (ok) { b = n / TT; t = n - b * TT; }
    const float* xp = x + ((size_t)b * CC) * TT + t;

    int wl = tid & 127;
    int wc = tid >> 7;

    int tx = tid & 15;
    int ty = tid >> 4;

    float acc[4][8];
#pragma unroll
    for (int i = 0; i < 4; ++i)
#pragma unroll
        for (int j = 0; j < 8; ++j) acc[i][j] = 0.f;

    for (int k0 = 0; k0 < CC; k0 += BK) {
#pragma unroll
        for (int i = 0; i < BK / 4; ++i) {
            int c = cl + i * 4;
            xs[c][nl] = ok ? xp[(size_t)(k0 + c) * TT] : 0.f;
        }
#pragma unroll
        for (int i = 0; i < BK / 2; ++i) {
            int c = wc + i * 2;
            ws[c][wl] = W[(k0 + c) * CC + wl];
        }
        __syncthreads();
#pragma unroll 8
        for (int k = 0; k < BK; ++k) {
            float4 a0 = *(const float4*)&xs[k][ty * 4];
            float4 b0 = *(const float4*)&ws[k][tx * 4];
            float4 b1 = *(const float4*)&ws[k][64 + tx * 4];
            acc[0][0] = fmaf(a0.x, b0.x, acc[0][0]); acc[0][1] = fmaf(a0.x, b0.y, acc[0][1]);
            acc[0][2] = fmaf(a0.x, b0.z, acc[0][2]); acc[0][3] = fmaf(a0.x, b0.w, acc[0][3]);
            acc[0][4] = fmaf(a0.x, b1.x, acc[0][4]); acc[0][5] = fmaf(a0.x, b1.y, acc[0][5]);
            acc[0][6] = fmaf(a0.x, b1.z, acc[0][6]); acc[0][7] = fmaf(a0.x, b1.w, acc[0][7]);
            acc[1][0] = fmaf(a0.y, b0.x, acc[1][0]); acc[1][1] = fmaf(a0.y, b0.y, acc[1][1]);
            acc[1][2] = fmaf(a0.y, b0.z, acc[1][2]); acc[1][3] = fmaf(a0.y, b0.w, acc[1][3]);
            acc[1][4] = fmaf(a0.y, b1.x, acc[1][4]); acc[1][5] = fmaf(a0.y, b1.y, acc[1][5]);
            acc[1][6] = fmaf(a0.y, b1.z, acc[1][6]); acc[1][7] = fmaf(a0.y, b1.w, acc[1][7]);
            acc[2][0] = fmaf(a0.z, b0.x, acc[2][0]); acc[2][1] = fmaf(a0.z, b0.y, acc[2][1]);
            acc[2][2] = fmaf(a0.z, b0.z, acc[2][2]); acc[2][3] = fmaf(a0.z, b0.w, acc[2][3]);
            acc[2][4] = fmaf(a0.z, b1.x, acc[2][4]); acc[2][5] = fmaf(a0.z, b1.y, acc[2][5]);
            acc[2][6] = fmaf(a0.z, b1.z, acc[2][6]); acc[2][7] = fmaf(a0.z, b1.w, acc[2][7]);
            acc[3][0] = fmaf(a0.w, b0.x, acc[3][0]); acc[3][1] = fmaf(a0.w, b0.y, acc[3][1]);
            acc[3][2] = fmaf(a0.w, b0.z, acc[3][2]); acc[3][3] = fmaf(a0.w, b0.w, acc[3][3]);
            acc[3][4] = fmaf(a0.w, b1.x, acc[3][4]); acc[3][5] = fmaf(a0.w, b1.y, acc[3][5]);
            acc[3][6] = fmaf(a0.w, b1.z, acc[3][6]); acc[3][7] = fmaf(a0.w, b1.w, acc[3][7]);
        }
        __syncthreads();
    }

#pragma unroll
    for (int i = 0; i < 4; ++i) {
        int no = n0 + ty * 4 + i;
        if (no < NN) {
            *(float4*)&h[(size_t)no * CC + tx * 4] =
                make_float4(acc[i][0], acc[i][1], acc[i][2], acc[i][3]);
            *(float4*)&h[(size_t)no * CC + 64 + tx * 4] =
                make_float4(acc[i][4], acc[i][5], acc[i][6], acc[i][7]);
        }
    }
}

// ---------------- aggregation: one wave per node, CSR gather ----------------
__global__ __launch_bounds__(256) void k_agg(const float* __restrict__ h,
                                             const int* __restrict__ off,
                                             const int* __restrict__ csr_src,
                                             const float* __restrict__ dinv,
                                             const float* __restrict__ bias,
                                             float* __restrict__ agg) {
    int lane = threadIdx.x & 63;
    int w    = threadIdx.x >> 6;
    int n    = blockIdx.x * 4 + w;
    if (n >= NN) return;
    const float2* h2 = (const float2*)h;
    float2 acc = make_float2(0.f, 0.f);
    int e0 = off[n], e1 = off[n + 1];
    for (int e = e0; e < e1; ++e) {
        int s   = csr_src[e];
        float f = dinv[s];
        float2 v = h2[(size_t)s * 64 + lane];
        acc.x = fmaf(f, v.x, acc.x);
        acc.y = fmaf(f, v.y, acc.y);
    }
    float di = dinv[n];
    float2 hv = h2[(size_t)n * 64 + lane];
    const float2* b2 = (const float2*)bias;
    float2 bb = b2[lane];
    float rx = fmaf(di, acc.x, di * di * hv.x) + bb.x;
    float ry = fmaf(di, acc.y, di * di * hv.y) + bb.y;
    rx = fmaxf(rx, 0.f);
    ry = fmaxf(ry, 0.f);
    ((float2*)agg)[(size_t)n * 64 + lane] = make_float2(rx, ry);
}

// ---------------- transpose [n][oc] -> [b][oc][t] ----------------
__global__ void k_trans(const float* __restrict__ agg, float* __restrict__ out) {
    __shared__ float tile[32][33];
    int t0 = blockIdx.x * 32;
    int o0 = blockIdx.y * 32;
    int b  = blockIdx.z;
    int tx = threadIdx.x, ty = threadIdx.y;         // 32 x 8
#pragma unroll
    for (int i = 0; i < 4; ++i) {
        int t = t0 + ty + i * 8;
        if (t < TT) tile[ty + i * 8][tx] = agg[(size_t)(b * TT + t) * CC + o0 + tx];
    }
    __syncthreads();
#pragma unroll
    for (int i = 0; i < 4; ++i) {
        int t  = t0 + tx;
        int oc = o0 + ty + i * 8;
        if (t < TT) out[((size_t)b * CC + oc) * TT + t] = tile[tx][ty + i * 8];
    }
}

extern "C" void kernel_launch(void* const* d_in, const int* in_sizes, int n_in,
                              void* d_out, int out_size, void* d_ws, size_t ws_size,
                              hipStream_t stream) {
    const float* x    = (const float*)d_in[0];
    const float* W    = (const float*)d_in[1];
    const float* bias = (const float*)d_in[2];
    const int*   ei   = (const int*)d_in[3];
    int E = in_sizes[3] / 2;
    const int* src = ei;
    const int* dst = ei + E;
    float* out = (float*)d_out;

    char* ws = (char*)d_ws;
    size_t o = 0;
    float* h    = (float*)(ws + o); o += (size_t)NN * CC * 4;       // 25.6 MB
    float* agg  = (float*)(ws + o); o += (size_t)NN * CC * 4;       // 25.6 MB
    int*   deg  = (int*)  (ws + o); o += (size_t)NN * 4;
    float* dinv = (float*)(ws + o); o += (size_t)NN * 4;
    int*   off  = (int*)  (ws + o); o += (size_t)(NN + 1) * 4 + 12; // keep 16B align
    int*   cur  = (int*)  (ws + o); o += (size_t)NN * 4;
    int*   bsum = (int*)  (ws + o); o += (size_t)NB * 4;
    int*   csrs = (int*)  (ws + o); o += (size_t)E * 4;

    hipMemsetAsync(deg, 0, (size_t)NN * 4, stream);
    hipMemsetAsync(cur, 0, (size_t)NN * 4, stream);

    k_deg  <<<(E + 255) / 256, 256, 0, stream>>>(dst, E, deg);
    k_bsum <<<NB, 256, 0, stream>>>(deg, bsum);
    k_scan2<<<NB, 256, 0, stream>>>(deg, bsum, off, dinv);
    k_fill <<<(E + 255) / 256, 256, 0, stream>>>(src, dst, E, off, cur, csrs);
    k_gemm <<<(NN + BN - 1) / BN, 256, 0, stream>>>(x, W, h);
    k_agg  <<<(NN + 3) / 4, 256, 0, stream>>>(h, off, csrs, dinv, bias, agg);
    dim3 tg((TT + 31) / 32, CC / 32, BB);
    k_trans<<<tg, dim3(32, 8), 0, stream>>>(agg, out);
}

// Round 4
// 241.288 us; speedup vs baseline: 2.2246x; 1.2087x over previous
//
#include <hip/hip_runtime.h>

#define TT 25000
#define BB 2
#define CC 128
#define NN (BB*TT)   // 50000 nodes
#define NB ((NN + 255) / 256)  // 196 scan blocks

__device__ inline unsigned short f2bf(float f) {
    unsigned int u = __float_as_uint(f);
    u += 0x7FFF + ((u >> 16) & 1);          // round-to-nearest-even
    return (unsigned short)(u >> 16);
}

// ---------------- degree count ----------------
__global__ void k_deg(const int* __restrict__ dst, int E, int* __restrict__ deg) {
    int i = blockIdx.x * blockDim.x + threadIdx.x;
    if (i < E) atomicAdd(&deg[dst[i]], 1);
}

// ---------------- scan pass 1: per-block sums ----------------
__global__ __launch_bounds__(256) void k_bsum(const int* __restrict__ deg,
                                              int* __restrict__ bsum) {
    __shared__ int red[256];
    int tid = threadIdx.x;
    int i = blockIdx.x * 256 + tid;
    red[tid] = (i < NN) ? deg[i] : 0;
    __syncthreads();
#pragma unroll
    for (int o = 128; o > 0; o >>= 1) {
        if (tid < o) red[tid] += red[tid + o];
        __syncthreads();
    }
    if (tid == 0) bsum[blockIdx.x] = red[0];
}

// ---------------- scan pass 2: block prefix + local scan + dinv ----------------
__global__ __launch_bounds__(256) void k_scan2(const int* __restrict__ deg,
                                               const int* __restrict__ bsum,
                                               int* __restrict__ off,
                                               float* __restrict__ dinv) {
    __shared__ int part[256];
    __shared__ int bpref;
    int tid = threadIdx.x;
    int i = blockIdx.x * 256 + tid;

    part[tid] = (tid < NB && tid < blockIdx.x) ? bsum[tid] : 0;
    __syncthreads();
#pragma unroll
    for (int o = 128; o > 0; o >>= 1) {
        if (tid < o) part[tid] += part[tid + o];
        __syncthreads();
    }
    if (tid == 0) bpref = part[0];
    __syncthreads();
    int base = bpref;
    __syncthreads();

    int v = (i < NN) ? deg[i] : 0;
    part[tid] = v;
    __syncthreads();
#pragma unroll
    for (int o = 1; o < 256; o <<= 1) {
        int u = (tid >= o) ? part[tid - o] : 0;
        __syncthreads();
        part[tid] += u;
        __syncthreads();
    }
    int incl = part[tid];
    if (i < NN) {
        off[i]  = base + incl - v;                  // exclusive
        dinv[i] = rsqrtf((float)(v + 1));
    }
    if (i == NN - 1) off[NN] = base + incl;         // == E
}

// ---------------- CSR fill ----------------
__global__ void k_fill(const int* __restrict__ src, const int* __restrict__ dst, int E,
                       const int* __restrict__ off, int* __restrict__ cur,
                       int* __restrict__ csr_src) {
    int i = blockIdx.x * blockDim.x + threadIdx.x;
    if (i < E) {
        int d = dst[i];
        int p = off[d] + atomicAdd(&cur[d], 1);
        csr_src[p] = src[i];
    }
}

// ---------------- GEMM: h[n][oc] = sum_c x[b][c][t] * W[c][oc], h in bf16 ----------------
#define BN 64
#define BK 32
__global__ __launch_bounds__(256) void k_gemm(const float* __restrict__ x,
                                              const float* __restrict__ W,
                                              unsigned short* __restrict__ h) {
    __shared__ float xs[BK][BN + 4];
    __shared__ float ws[BK][CC + 4];
    int tid = threadIdx.x;
    int n0 = blockIdx.x * BN;

    int nl = tid & 63;
    int cl = tid >> 6;
    int n = n0 + nl;
    bool ok = (n < NN);
    int b = 0, t = 0;
    if (ok) { b = n / TT; t = n - b * TT; }
    const float* xp = x + ((size_t)b * CC) * TT + t;

    int wl = tid & 127;
    int wc = tid >> 7;

    int tx = tid & 15;
    int ty = tid >> 4;

    float acc[4][8];
#pragma unroll
    for (int i = 0; i < 4; ++i)
#pragma unroll
        for (int j = 0; j < 8; ++j) acc[i][j] = 0.f;

    for (int k0 = 0; k0 < CC; k0 += BK) {
#pragma unroll
        for (int i = 0; i < BK / 4; ++i) {
            int c = cl + i * 4;
            xs[c][nl] = ok ? xp[(size_t)(k0 + c) * TT] : 0.f;
        }
#pragma unroll
        for (int i = 0; i < BK / 2; ++i) {
            int c = wc + i * 2;
            ws[c][wl] = W[(k0 + c) * CC + wl];
        }
        __syncthreads();
#pragma unroll 8
        for (int k = 0; k < BK; ++k) {
            float4 a0 = *(const float4*)&xs[k][ty * 4];
            float4 b0 = *(const float4*)&ws[k][tx * 4];
            float4 b1 = *(const float4*)&ws[k][64 + tx * 4];
            acc[0][0] = fmaf(a0.x, b0.x, acc[0][0]); acc[0][1] = fmaf(a0.x, b0.y, acc[0][1]);
            acc[0][2] = fmaf(a0.x, b0.z, acc[0][2]); acc[0][3] = fmaf(a0.x, b0.w, acc[0][3]);
            acc[0][4] = fmaf(a0.x, b1.x, acc[0][4]); acc[0][5] = fmaf(a0.x, b1.y, acc[0][5]);
            acc[0][6] = fmaf(a0.x, b1.z, acc[0][6]); acc[0][7] = fmaf(a0.x, b1.w, acc[0][7]);
            acc[1][0] = fmaf(a0.y, b0.x, acc[1][0]); acc[1][1] = fmaf(a0.y, b0.y, acc[1][1]);
            acc[1][2] = fmaf(a0.y, b0.z, acc[1][2]); acc[1][3] = fmaf(a0.y, b0.w, acc[1][3]);
            acc[1][4] = fmaf(a0.y, b1.x, acc[1][4]); acc[1][5] = fmaf(a0.y, b1.y, acc[1][5]);
            acc[1][6] = fmaf(a0.y, b1.z, acc[1][6]); acc[1][7] = fmaf(a0.y, b1.w, acc[1][7]);
            acc[2][0] = fmaf(a0.z, b0.x, acc[2][0]); acc[2][1] = fmaf(a0.z, b0.y, acc[2][1]);
            acc[2][2] = fmaf(a0.z, b0.z, acc[2][2]); acc[2][3] = fmaf(a0.z, b0.w, acc[2][3]);
            acc[2][4] = fmaf(a0.z, b1.x, acc[2][4]); acc[2][5] = fmaf(a0.z, b1.y, acc[2][5]);
            acc[2][6] = fmaf(a0.z, b1.z, acc[2][6]); acc[2][7] = fmaf(a0.z, b1.w, acc[2][7]);
            acc[3][0] = fmaf(a0.w, b0.x, acc[3][0]); acc[3][1] = fmaf(a0.w, b0.y, acc[3][1]);
            acc[3][2] = fmaf(a0.w, b0.z, acc[3][2]); acc[3][3] = fmaf(a0.w, b0.w, acc[3][3]);
            acc[3][4] = fmaf(a0.w, b1.x, acc[3][4]); acc[3][5] = fmaf(a0.w, b1.y, acc[3][5]);
            acc[3][6] = fmaf(a0.w, b1.z, acc[3][6]); acc[3][7] = fmaf(a0.w, b1.w, acc[3][7]);
        }
        __syncthreads();
    }

#pragma unroll
    for (int i = 0; i < 4; ++i) {
        int no = n0 + ty * 4 + i;
        if (no < NN) {
            ushort4 p0, p1;
            p0.x = f2bf(acc[i][0]); p0.y = f2bf(acc[i][1]);
            p0.z = f2bf(acc[i][2]); p0.w = f2bf(acc[i][3]);
            p1.x = f2bf(acc[i][4]); p1.y = f2bf(acc[i][5]);
            p1.z = f2bf(acc[i][6]); p1.w = f2bf(acc[i][7]);
            *(ushort4*)&h[(size_t)no * CC + tx * 4]      = p0;
            *(ushort4*)&h[(size_t)no * CC + 64 + tx * 4] = p1;
        }
    }
}

// ---------------- aggregation: one wave per node, CSR gather (bf16 h) ----------------
__global__ __launch_bounds__(256) void k_agg(const unsigned int* __restrict__ hb,
                                             const int* __restrict__ off,
                                             const int* __restrict__ csr_src,
                                             const float* __restrict__ dinv,
                                             const float* __restrict__ bias,
                                             float* __restrict__ agg) {
    int lane = threadIdx.x & 63;
    int w    = threadIdx.x >> 6;
    int n    = blockIdx.x * 4 + w;
    if (n >= NN) return;
    float ax = 0.f, ay = 0.f;
    int e0 = off[n], e1 = off[n + 1];
    int e = e0;
    for (; e + 4 <= e1; e += 4) {
        int s0 = csr_src[e], s1 = csr_src[e + 1], s2 = csr_src[e + 2], s3 = csr_src[e + 3];
        float f0 = dinv[s0], f1 = dinv[s1], f2 = dinv[s2], f3 = dinv[s3];
        unsigned int v0 = hb[(size_t)s0 * 64 + lane];
        unsigned int v1 = hb[(size_t)s1 * 64 + lane];
        unsigned int v2 = hb[(size_t)s2 * 64 + lane];
        unsigned int v3 = hb[(size_t)s3 * 64 + lane];
        ax = fmaf(f0, __uint_as_float(v0 << 16), ax);
        ay = fmaf(f0, __uint_as_float(v0 & 0xFFFF0000u), ay);
        ax = fmaf(f1, __uint_as_float(v1 << 16), ax);
        ay = fmaf(f1, __uint_as_float(v1 & 0xFFFF0000u), ay);
        ax = fmaf(f2, __uint_as_float(v2 << 16), ax);
        ay = fmaf(f2, __uint_as_float(v2 & 0xFFFF0000u), ay);
        ax = fmaf(f3, __uint_as_float(v3 << 16), ax);
        ay = fmaf(f3, __uint_as_float(v3 & 0xFFFF0000u), ay);
    }
    for (; e < e1; ++e) {
        int s = csr_src[e];
        float f = dinv[s];
        unsigned int v = hb[(size_t)s * 64 + lane];
        ax = fmaf(f, __uint_as_float(v << 16), ax);
        ay = fmaf(f, __uint_as_float(v & 0xFFFF0000u), ay);
    }
    float di = dinv[n];
    unsigned int hv = hb[(size_t)n * 64 + lane];
    float hx = __uint_as_float(hv << 16);
    float hy = __uint_as_float(hv & 0xFFFF0000u);
    const float2* b2 = (const float2*)bias;
    float2 bb = b2[lane];
    float rx = fmaf(di, ax, di * di * hx) + bb.x;
    float ry = fmaf(di, ay, di * di * hy) + bb.y;
    rx = fmaxf(rx, 0.f);
    ry = fmaxf(ry, 0.f);
    ((float2*)agg)[(size_t)n * 64 + lane] = make_float2(rx, ry);
}

// ---------------- transpose [n][oc] -> [b][oc][t] ----------------
__global__ void k_trans(const float* __restrict__ agg, float* __restrict__ out) {
    __shared__ float tile[32][33];
    int t0 = blockIdx.x * 32;
    int o0 = blockIdx.y * 32;
    int b  = blockIdx.z;
    int tx = threadIdx.x, ty = threadIdx.y;         // 32 x 8
#pragma unroll
    for (int i = 0; i < 4; ++i) {
        int t = t0 + ty + i * 8;
        if (t < TT) tile[ty + i * 8][tx] = agg[(size_t)(b * TT + t) * CC + o0 + tx];
    }
    __syncthreads();
#pragma unroll
    for (int i = 0; i < 4; ++i) {
        int t  = t0 + tx;
        int oc = o0 + ty + i * 8;
        if (t < TT) out[((size_t)b * CC + oc) * TT + t] = tile[tx][ty + i * 8];
    }
}

extern "C" void kernel_launch(void* const* d_in, const int* in_sizes, int n_in,
                              void* d_out, int out_size, void* d_ws, size_t ws_size,
                              hipStream_t stream) {
    const float* x    = (const float*)d_in[0];
    const float* W    = (const float*)d_in[1];
    const float* bias = (const float*)d_in[2];
    const int*   ei   = (const int*)d_in[3];
    int E = in_sizes[3] / 2;
    const int* src = ei;
    const int* dst = ei + E;
    float* out = (float*)d_out;

    char* ws = (char*)d_ws;
    size_t o = 0;
    unsigned short* h = (unsigned short*)(ws + o); o += (size_t)NN * CC * 2;  // 12.8 MB
    float* agg  = (float*)(ws + o); o += (size_t)NN * CC * 4;                 // 25.6 MB
    int*   deg  = (int*)  (ws + o); o += (size_t)NN * 4;
    float* dinv = (float*)(ws + o); o += (size_t)NN * 4;
    int*   off  = (int*)  (ws + o); o += (size_t)(NN + 1) * 4 + 12;
    int*   cur  = (int*)  (ws + o); o += (size_t)NN * 4;
    int*   bsum = (int*)  (ws + o); o += (size_t)NB * 4;
    int*   csrs = (int*)  (ws + o); o += (size_t)E * 4;

    hipMemsetAsync(deg, 0, (size_t)NN * 4, stream);
    hipMemsetAsync(cur, 0, (size_t)NN * 4, stream);

    k_deg  <<<(E + 255) / 256, 256, 0, stream>>>(dst, E, deg);
    k_bsum <<<NB, 256, 0, stream>>>(deg, bsum);
    k_scan2<<<NB, 256, 0, stream>>>(deg, bsum, off, dinv);
    k_fill <<<(E + 255) / 256, 256, 0, stream>>>(src, dst, E, off, cur, csrs);
    k_gemm <<<(NN + BN - 1) / BN, 256, 0, stream>>>(x, W, h);
    k_agg  <<<(NN + 3) / 4, 256, 0, stream>>>((const unsigned int*)h, off, csrs, dinv, bias, agg);
    dim3 tg((TT + 31) / 32, CC / 32, BB);
    k_trans<<<tg, dim3(32, 8), 0, stream>>>(agg, out);
}

// Round 5
// 213.764 us; speedup vs baseline: 2.5111x; 1.1288x over previous
//
#include <hip/hip_runtime.h>

#define TT 25000
#define BB 2
#define CC 128
#define NN (BB*TT)   // 50000 nodes
#define NB ((NN + 255) / 256)  // 196 scan blocks

__device__ inline unsigned short f2bf(float f) {
    unsigned int u = __float_as_uint(f);
    u += 0x7FFF + ((u >> 16) & 1);          // round-to-nearest-even
    return (unsigned short)(u >> 16);
}

// ---------------- degree count + per-edge sequence number ----------------
// 2 edges/thread for atomic MLP; eseq[i] = arrival order of edge i at its dst.
__global__ __launch_bounds__(256) void k_deg(const int* __restrict__ dst, int E,
                                             int* __restrict__ deg,
                                             int* __restrict__ eseq) {
    int i0 = blockIdx.x * 512 + threadIdx.x;
    int i1 = i0 + 256;
    int d0 = 0, d1 = 0;
    bool ok0 = (i0 < E), ok1 = (i1 < E);
    if (ok0) d0 = dst[i0];
    if (ok1) d1 = dst[i1];
    if (ok0) eseq[i0] = atomicAdd(&deg[d0], 1);
    if (ok1) eseq[i1] = atomicAdd(&deg[d1], 1);
}

// ---------------- scan pass 1: per-block sums ----------------
__global__ __launch_bounds__(256) void k_bsum(const int* __restrict__ deg,
                                              int* __restrict__ bsum) {
    __shared__ int red[256];
    int tid = threadIdx.x;
    int i = blockIdx.x * 256 + tid;
    red[tid] = (i < NN) ? deg[i] : 0;
    __syncthreads();
#pragma unroll
    for (int o = 128; o > 0; o >>= 1) {
        if (tid < o) red[tid] += red[tid + o];
        __syncthreads();
    }
    if (tid == 0) bsum[blockIdx.x] = red[0];
}

// ---------------- scan pass 2: block prefix + local scan + dinv ----------------
__global__ __launch_bounds__(256) void k_scan2(const int* __restrict__ deg,
                                               const int* __restrict__ bsum,
                                               int* __restrict__ off,
                                               float* __restrict__ dinv) {
    __shared__ int part[256];
    __shared__ int bpref;
    int tid = threadIdx.x;
    int i = blockIdx.x * 256 + tid;

    part[tid] = (tid < NB && tid < blockIdx.x) ? bsum[tid] : 0;
    __syncthreads();
#pragma unroll
    for (int o = 128; o > 0; o >>= 1) {
        if (tid < o) part[tid] += part[tid + o];
        __syncthreads();
    }
    if (tid == 0) bpref = part[0];
    __syncthreads();
    int base = bpref;
    __syncthreads();

    int v = (i < NN) ? deg[i] : 0;
    part[tid] = v;
    __syncthreads();
#pragma unroll
    for (int o = 1; o < 256; o <<= 1) {
        int u = (tid >= o) ? part[tid - o] : 0;
        __syncthreads();
        part[tid] += u;
        __syncthreads();
    }
    int incl = part[tid];
    if (i < NN) {
        off[i]  = base + incl - v;                  // exclusive
        dinv[i] = rsqrtf((float)(v + 1));
    }
    if (i == NN - 1) off[NN] = base + incl;         // == E
}

// ---------------- CSR fill: atomic-free scatter ----------------
__global__ __launch_bounds__(256) void k_fill(const int* __restrict__ src,
                                              const int* __restrict__ dst, int E,
                                              const int* __restrict__ off,
                                              const int* __restrict__ eseq,
                                              int* __restrict__ csr_src) {
    int i = blockIdx.x * blockDim.x + threadIdx.x;
    if (i < E) {
        int d = dst[i];
        csr_src[off[d] + eseq[i]] = src[i];
    }
}

// ---------------- GEMM: h[n][oc] = sum_c x[b][c][t] * W[c][oc], h in bf16 ----------------
#define BN 64
#define BK 32
__global__ __launch_bounds__(256) void k_gemm(const float* __restrict__ x,
                                              const float* __restrict__ W,
                                              unsigned short* __restrict__ h) {
    __shared__ float xs[BK][BN + 4];
    __shared__ float ws[BK][CC + 4];
    int tid = threadIdx.x;
    int n0 = blockIdx.x * BN;

    int nl = tid & 63;
    int cl = tid >> 6;
    int n = n0 + nl;
    bool ok = (n < NN);
    int b = 0, t = 0;
    if (ok) { b = n / TT; t = n - b * TT; }
    const float* xp = x + ((size_t)b * CC) * TT + t;

    int wl = tid & 127;
    int wc = tid >> 7;

    int tx = tid & 15;
    int ty = tid >> 4;

    float acc[4][8];
#pragma unroll
    for (int i = 0; i < 4; ++i)
#pragma unroll
        for (int j = 0; j < 8; ++j) acc[i][j] = 0.f;

    for (int k0 = 0; k0 < CC; k0 += BK) {
#pragma unroll
        for (int i = 0; i < BK / 4; ++i) {
            int c = cl + i * 4;
            xs[c][nl] = ok ? xp[(size_t)(k0 + c) * TT] : 0.f;
        }
#pragma unroll
        for (int i = 0; i < BK / 2; ++i) {
            int c = wc + i * 2;
            ws[c][wl] = W[(k0 + c) * CC + wl];
        }
        __syncthreads();
#pragma unroll 8
        for (int k = 0; k < BK; ++k) {
            float4 a0 = *(const float4*)&xs[k][ty * 4];
            float4 b0 = *(const float4*)&ws[k][tx * 4];
            float4 b1 = *(const float4*)&ws[k][64 + tx * 4];
            acc[0][0] = fmaf(a0.x, b0.x, acc[0][0]); acc[0][1] = fmaf(a0.x, b0.y, acc[0][1]);
            acc[0][2] = fmaf(a0.x, b0.z, acc[0][2]); acc[0][3] = fmaf(a0.x, b0.w, acc[0][3]);
            acc[0][4] = fmaf(a0.x, b1.x, acc[0][4]); acc[0][5] = fmaf(a0.x, b1.y, acc[0][5]);
            acc[0][6] = fmaf(a0.x, b1.z, acc[0][6]); acc[0][7] = fmaf(a0.x, b1.w, acc[0][7]);
            acc[1][0] = fmaf(a0.y, b0.x, acc[1][0]); acc[1][1] = fmaf(a0.y, b0.y, acc[1][1]);
            acc[1][2] = fmaf(a0.y, b0.z, acc[1][2]); acc[1][3] = fmaf(a0.y, b0.w, acc[1][3]);
            acc[1][4] = fmaf(a0.y, b1.x, acc[1][4]); acc[1][5] = fmaf(a0.y, b1.y, acc[1][5]);
            acc[1][6] = fmaf(a0.y, b1.z, acc[1][6]); acc[1][7] = fmaf(a0.y, b1.w, acc[1][7]);
            acc[2][0] = fmaf(a0.z, b0.x, acc[2][0]); acc[2][1] = fmaf(a0.z, b0.y, acc[2][1]);
            acc[2][2] = fmaf(a0.z, b0.z, acc[2][2]); acc[2][3] = fmaf(a0.z, b0.w, acc[2][3]);
            acc[2][4] = fmaf(a0.z, b1.x, acc[2][4]); acc[2][5] = fmaf(a0.z, b1.y, acc[2][5]);
            acc[2][6] = fmaf(a0.z, b1.z, acc[2][6]); acc[2][7] = fmaf(a0.z, b1.w, acc[2][7]);
            acc[3][0] = fmaf(a0.w, b0.x, acc[3][0]); acc[3][1] = fmaf(a0.w, b0.y, acc[3][1]);
            acc[3][2] = fmaf(a0.w, b0.z, acc[3][2]); acc[3][3] = fmaf(a0.w, b0.w, acc[3][3]);
            acc[3][4] = fmaf(a0.w, b1.x, acc[3][4]); acc[3][5] = fmaf(a0.w, b1.y, acc[3][5]);
            acc[3][6] = fmaf(a0.w, b1.z, acc[3][6]); acc[3][7] = fmaf(a0.w, b1.w, acc[3][7]);
        }
        __syncthreads();
    }

#pragma unroll
    for (int i = 0; i < 4; ++i) {
        int no = n0 + ty * 4 + i;
        if (no < NN) {
            ushort4 p0, p1;
            p0.x = f2bf(acc[i][0]); p0.y = f2bf(acc[i][1]);
            p0.z = f2bf(acc[i][2]); p0.w = f2bf(acc[i][3]);
            p1.x = f2bf(acc[i][4]); p1.y = f2bf(acc[i][5]);
            p1.z = f2bf(acc[i][6]); p1.w = f2bf(acc[i][7]);
            *(ushort4*)&h[(size_t)no * CC + tx * 4]      = p0;
            *(ushort4*)&h[(size_t)no * CC + 64 + tx * 4] = p1;
        }
    }
}

// ---------------- aggregation: one wave per node, CSR gather (bf16 h) ----------------
__global__ __launch_bounds__(256) void k_agg(const unsigned int* __restrict__ hb,
                                             const int* __restrict__ off,
                                             const int* __restrict__ csr_src,
                                             const float* __restrict__ dinv,
                                             const float* __restrict__ bias,
                                             float* __restrict__ agg) {
    int lane = threadIdx.x & 63;
    int w    = threadIdx.x >> 6;
    int n    = blockIdx.x * 4 + w;
    if (n >= NN) return;
    float ax = 0.f, ay = 0.f;
    int e0 = off[n], e1 = off[n + 1];
    int e = e0;
    for (; e + 4 <= e1; e += 4) {
        int s0 = csr_src[e], s1 = csr_src[e + 1], s2 = csr_src[e + 2], s3 = csr_src[e + 3];
        float f0 = dinv[s0], f1 = dinv[s1], f2 = dinv[s2], f3 = dinv[s3];
        unsigned int v0 = hb[(size_t)s0 * 64 + lane];
        unsigned int v1 = hb[(size_t)s1 * 64 + lane];
        unsigned int v2 = hb[(size_t)s2 * 64 + lane];
        unsigned int v3 = hb[(size_t)s3 * 64 + lane];
        ax = fmaf(f0, __uint_as_float(v0 << 16), ax);
        ay = fmaf(f0, __uint_as_float(v0 & 0xFFFF0000u), ay);
        ax = fmaf(f1, __uint_as_float(v1 << 16), ax);
        ay = fmaf(f1, __uint_as_float(v1 & 0xFFFF0000u), ay);
        ax = fmaf(f2, __uint_as_float(v2 << 16), ax);
        ay = fmaf(f2, __uint_as_float(v2 & 0xFFFF0000u), ay);
        ax = fmaf(f3, __uint_as_float(v3 << 16), ax);
        ay = fmaf(f3, __uint_as_float(v3 & 0xFFFF0000u), ay);
    }
    for (; e < e1; ++e) {
        int s = csr_src[e];
        float f = dinv[s];
        unsigned int v = hb[(size_t)s * 64 + lane];
        ax = fmaf(f, __uint_as_float(v << 16), ax);
        ay = fmaf(f, __uint_as_float(v & 0xFFFF0000u), ay);
    }
    float di = dinv[n];
    unsigned int hv = hb[(size_t)n * 64 + lane];
    float hx = __uint_as_float(hv << 16);
    float hy = __uint_as_float(hv & 0xFFFF0000u);
    const float2* b2 = (const float2*)bias;
    float2 bb = b2[lane];
    float rx = fmaf(di, ax, di * di * hx) + bb.x;
    float ry = fmaf(di, ay, di * di * hy) + bb.y;
    rx = fmaxf(rx, 0.f);
    ry = fmaxf(ry, 0.f);
    ((float2*)agg)[(size_t)n * 64 + lane] = make_float2(rx, ry);
}

// ---------------- transpose [n][oc] -> [b][oc][t] ----------------
__global__ void k_trans(const float* __restrict__ agg, float* __restrict__ out) {
    __shared__ float tile[32][33];
    int t0 = blockIdx.x * 32;
    int o0 = blockIdx.y * 32;
    int b  = blockIdx.z;
    int tx = threadIdx.x, ty = threadIdx.y;         // 32 x 8
#pragma unroll
    for (int i = 0; i < 4; ++i) {
        int t = t0 + ty + i * 8;
        if (t < TT) tile[ty + i * 8][tx] = agg[(size_t)(b * TT + t) * CC + o0 + tx];
    }
    __syncthreads();
#pragma unroll
    for (int i = 0; i < 4; ++i) {
        int t  = t0 + tx;
        int oc = o0 + ty + i * 8;
        if (t < TT) out[((size_t)b * CC + oc) * TT + t] = tile[tx][ty + i * 8];
    }
}

extern "C" void kernel_launch(void* const* d_in, const int* in_sizes, int n_in,
                              void* d_out, int out_size, void* d_ws, size_t ws_size,
                              hipStream_t stream) {
    const float* x    = (const float*)d_in[0];
    const float* W    = (const float*)d_in[1];
    const float* bias = (const float*)d_in[2];
    const int*   ei   = (const int*)d_in[3];
    int E = in_sizes[3] / 2;
    const int* src = ei;
    const int* dst = ei + E;
    float* out = (float*)d_out;

    char* ws = (char*)d_ws;
    size_t o = 0;
    unsigned short* h = (unsigned short*)(ws + o); o += (size_t)NN * CC * 2;  // 12.8 MB
    float* agg  = (float*)(ws + o); o += (size_t)NN * CC * 4;                 // 25.6 MB
    int*   deg  = (int*)  (ws + o); o += (size_t)NN * 4;
    float* dinv = (float*)(ws + o); o += (size_t)NN * 4;
    int*   off  = (int*)  (ws + o); o += (size_t)(NN + 1) * 4 + 12;
    int*   bsum = (int*)  (ws + o); o += (size_t)((NB + 3) & ~3) * 4;
    int*   eseq = (int*)  (ws + o); o += (size_t)E * 4;
    int*   csrs = (int*)  (ws + o); o += (size_t)E * 4;

    hipMemsetAsync(deg, 0, (size_t)NN * 4, stream);

    k_deg  <<<(E + 511) / 512, 256, 0, stream>>>(dst, E, deg, eseq);
    k_bsum <<<NB, 256, 0, stream>>>(deg, bsum);
    k_scan2<<<NB, 256, 0, stream>>>(deg, bsum, off, dinv);
    k_fill <<<(E + 255) / 256, 256, 0, stream>>>(src, dst, E, off, eseq, csrs);
    k_gemm <<<(NN + BN - 1) / BN, 256, 0, stream>>>(x, W, h);
    k_agg  <<<(NN + 3) / 4, 256, 0, stream>>>((const unsigned int*)h, off, csrs, dinv, bias, agg);
    dim3 tg((TT + 31) / 32, CC / 32, BB);
    k_trans<<<tg, dim3(32, 8), 0, stream>>>(agg, out);
}